// Round 17
// baseline (280.983 us; speedup 1.0000x reference)
//
#include <hip/hip_runtime.h>
#include <stdint.h>

#define FEAT 128
#define ECH 2048   // edges per econv block
#define CAP 200000 // per-partition edge capacity
#define SCB 512    // scatter blocks in fused k_sg

typedef short bf16x8 __attribute__((ext_vector_type(8)));
typedef float f32x4 __attribute__((ext_vector_type(4)));
typedef float f32x2 __attribute__((ext_vector_type(2)));

__device__ __forceinline__ float bfs(unsigned short u) {
    uint32_t t = ((uint32_t)u) << 16;
    return __builtin_bit_cast(float, t);
}
__device__ __forceinline__ unsigned short f2bf(float f) {
    uint32_t u = __builtin_bit_cast(uint32_t, f);
    u += 0x7fffu + ((u >> 16) & 1u);
    return (unsigned short)(u >> 16);
}

// ---- fused prep: econv blocks [0,NE) | W blocks [NE,NE+64) | bias [+18) -
// edges packed: uint32 = dst<<16 | src (node ids < 65536)
__launch_bounds__(256)
__global__ void k_prep(const int* __restrict__ ei,
                       uint32_t* __restrict__ ebuf,
                       int* __restrict__ bcnt, int* __restrict__ deg,
                       int E, int n, int psz, int NE,
                       const void* W1, const void* W2,
                       const void* b1, const void* b2,
                       const void* Wfc, const void* bfc,
                       unsigned short* Wth1, unsigned short* Wth2,
                       float* b1f, float* b2f, float* Wfcf, float* bfcf) {
    int t = threadIdx.x;

    if ((int)blockIdx.x >= NE) {
        __shared__ int hits;
        int blk = blockIdx.x - NE;
        const void* sampsrc = (blk < 32) ? W1 : (blk < 64 ? W2 : Wfc);
        const uint32_t* samp = (const uint32_t*)sampsrc;
        if (t == 0) hits = 0;
        __syncthreads();
        unsigned ew = (samp[t] >> 7) & 0xFFu;
        unsigned long long bl = __ballot(ew >= 0x60u && ew <= 0x90u);
        if ((t & 63) == 0) atomicAdd(&hits, (int)__popcll(bl));
        __syncthreads();
        int isbf = (2 * hits > 256);

        if (blk < 64) {
            const void* W = (blk < 32) ? W1 : W2;
            unsigned short* th = (blk < 32) ? Wth1 : Wth2;
            int base = (blk & 31) * 512;
            #pragma unroll
            for (int j = 0; j < 2; j++) {
                int idx = base + t * 2 + j;
                int nn = idx >> 7, k = idx & 127;
                int si = k * 128 + nn;
                float f = isbf ? bfs(((const unsigned short*)W)[si])
                               : ((const float*)W)[si];
                th[nn * 128 + k] = f2bf(f);
            }
        } else {
            int i = (blk - 64) * 256 + t;
            if (i >= 4384) return;
            const void* src; float* dst; int off;
            if (i < 128)       { src = b1;  dst = b1f;  off = i; }
            else if (i < 256)  { src = b2;  dst = b2f;  off = i - 128; }
            else if (i < 4352) { src = Wfc; dst = Wfcf; off = i - 256; }
            else               { src = bfc; dst = bfcf; off = i - 4352; }
            dst[off] = isbf ? bfs(((const unsigned short*)src)[off])
                            : ((const float*)src)[off];
        }
        return;
    }

    // ---- econv part (+ zero its deg slice) ----
    __shared__ int lflag;
    __shared__ int cnt[8], lofs[8], gbase[8];
    __shared__ uint32_t stage[ECH];
    __shared__ char sb[ECH];
    if (t < 128) {
        int di = blockIdx.x * 128 + t;
        if (di < n) deg[di] = 0;
    }
    if (t == 0) lflag = 0;
    if (t < 8) cnt[t] = 0;
    __syncthreads();
    if (ei[1 + 2 * t] != 0) atomicOr(&lflag, 1);   // odd words: 0 => int64
    __syncthreads();
    int is32 = lflag;

    int base = blockIdx.x * ECH;
    uint32_t pe[8]; int p[8], slot[8];
    #pragma unroll
    for (int j = 0; j < 8; j++) {
        int e = base + j * 256 + t;
        if (e < E) {
            int ss = is32 ? ei[e]     : ei[2 * e];
            int dd = is32 ? ei[E + e] : ei[2 * E + 2 * e];
            if ((unsigned)ss >= (unsigned)n) ss = 0;
            if ((unsigned)dd >= (unsigned)n) dd = 0;
            int pp = dd / psz;
            if (pp > 7) pp = 7;
            p[j] = pp;
            pe[j] = ((uint32_t)dd << 16) | (uint32_t)ss;
            slot[j] = atomicAdd(&cnt[pp], 1);
        } else { p[j] = -1; pe[j] = 0; }
    }
    __syncthreads();
    if (t == 0) {
        int acc = 0;
        #pragma unroll
        for (int i = 0; i < 8; i++) { lofs[i] = acc; acc += cnt[i]; }
    }
    __syncthreads();
    if (t < 8) gbase[t] = atomicAdd(&bcnt[t], cnt[t]);
    __syncthreads();
    #pragma unroll
    for (int j = 0; j < 8; j++) {
        if (p[j] >= 0) {
            int pos = lofs[p[j]] + slot[j];
            stage[pos] = pe[j];
            sb[pos] = (char)p[j];
        }
    }
    __syncthreads();
    int tot = lofs[7] + cnt[7];
    for (int i = t; i < tot; i += 256) {
        int pp = sb[i];
        int off = gbase[pp] + (i - lofs[pp]);
        if (off < CAP) ebuf[(size_t)pp * CAP + off] = stage[i];
    }
}

// ---- partitioned degree count (packed edges) ----------------------------
__launch_bounds__(256)
__global__ void k_degp(const uint32_t* __restrict__ ebuf, const int* __restrict__ bcnt,
                       int* __restrict__ deg) {
    int p = blockIdx.x & 7;
    int nb = gridDim.x >> 3;
    int cnt = bcnt[p]; if (cnt > CAP) cnt = CAP;
    const uint32_t* eb = ebuf + (size_t)p * CAP;
    for (int i = (blockIdx.x >> 3) * 256 + threadIdx.x; i < cnt; i += nb * 256)
        atomicAdd(&deg[eb[i] >> 16], 1);
}

// ---- block sums (+ fused dinv) ------------------------------------------
__global__ void k_bsum(const int* __restrict__ deg, int* __restrict__ bsum,
                       float* __restrict__ dinv, int n) {
    __shared__ int ws[4];
    int t = threadIdx.x, lane = t & 63, w = t >> 6;
    int idx = blockIdx.x * 256 + t;
    int v = (idx < n) ? deg[idx] : 0;
    if (idx < n) dinv[idx] = rsqrtf((float)(v + 1));  // +1 self-loop
    int r = v;
    #pragma unroll
    for (int off = 32; off > 0; off >>= 1) r += __shfl_down(r, off, 64);
    if (lane == 0) ws[w] = r;
    __syncthreads();
    if (t == 0) bsum[blockIdx.x] = ws[0] + ws[1] + ws[2] + ws[3];
}

// ---- apply with self-computed block offset ------------------------------
__launch_bounds__(256)
__global__ void k_bapply2(const int* __restrict__ deg, const int* __restrict__ bsum,
                          int* __restrict__ row_ptr, int* __restrict__ cursor,
                          int n, int nb) {
    __shared__ int wred[4];
    __shared__ int wsum[4];
    __shared__ int boffs;
    int b = blockIdx.x, t = threadIdx.x, lane = t & 63, w = t >> 6;

    int pv = (t < b && t < nb) ? bsum[t] : 0;
    #pragma unroll
    for (int off = 32; off > 0; off >>= 1) pv += __shfl_down(pv, off, 64);
    if (lane == 0) wred[w] = pv;
    __syncthreads();
    if (t == 0) boffs = wred[0] + wred[1] + wred[2] + wred[3];
    __syncthreads();

    int idx = b * 256 + t;
    int v = (idx < n) ? deg[idx] : 0;
    int s = v;
    #pragma unroll
    for (int off = 1; off < 64; off <<= 1) {
        int x = __shfl_up(s, off, 64);
        if (lane >= off) s += x;
    }
    if (lane == 63) wsum[w] = s;
    __syncthreads();
    if (t == 0) {
        int acc = 0;
        #pragma unroll
        for (int i = 0; i < 4; i++) { int x = wsum[i]; wsum[i] = acc; acc += x; }
    }
    __syncthreads();
    int ex = boffs + s - v + wsum[w];
    if (idx < n) {
        row_ptr[idx] = ex;
        cursor[idx]  = ex;
    }
    if (idx == n - 1) row_ptr[n] = ex + v;
}

// ---- GEMM tile body: hs8 = fp8(dinv[row]*(X @ W)) -----------------------
__device__ __forceinline__ void gemm_body(const void* __restrict__ X,
                                          const unsigned short* __restrict__ Wth,
                                          const float* __restrict__ dinv,
                                          uint32_t* __restrict__ hs8,
                                          int n, int tile, int l,
                                          unsigned char* __restrict__ ldsrow) {
    int quad = l >> 4;
    int m16 = l & 15;
    int r0 = tile * 16;

    unsigned ew = (((const uint32_t*)X)[l] >> 7) & 0xFFu;
    unsigned long long bl = __ballot(ew >= 0x60u && ew <= 0x90u);
    int isbf = ((int)__popcll(bl) * 2 > 64) ? 1 : 0;

    int ra = r0 + m16;
    if (ra > n - 1) ra = n - 1;
    bf16x8 ah[4];
    if (isbf) {
        const int4* Xv = (const int4*)X;
        #pragma unroll
        for (int kt = 0; kt < 4; kt++)
            ah[kt] = __builtin_bit_cast(bf16x8, Xv[ra * 16 + kt * 4 + quad]);
    } else {
        const float4* Xf = (const float4*)X;
        #pragma unroll
        for (int kt = 0; kt < 4; kt++) {
            int jj = kt * 4 + quad;
            float4 fa = Xf[ra * 32 + jj * 2];
            float4 fb = Xf[ra * 32 + jj * 2 + 1];
            float v[8] = {fa.x, fa.y, fa.z, fa.w, fb.x, fb.y, fb.z, fb.w};
            bf16x8 h;
            #pragma unroll
            for (int j = 0; j < 8; j++) h[j] = (short)f2bf(v[j]);
            ah[kt] = h;
        }
    }

    float dv[4];
    #pragma unroll
    for (int reg = 0; reg < 4; reg++) {
        int row = r0 + quad * 4 + reg;
        if (row > n - 1) row = n - 1;
        dv[reg] = dinv[row];
    }

    const int4* Wvh = (const int4*)Wth;
    #pragma unroll
    for (int nt = 0; nt < 8; nt++) {
        f32x4 acc = {0.f, 0.f, 0.f, 0.f};
        int brow = (nt * 16 + m16) * 16;
        #pragma unroll
        for (int kt = 0; kt < 4; kt++) {
            bf16x8 bh = __builtin_bit_cast(bf16x8, Wvh[brow + kt * 4 + quad]);
            acc = __builtin_amdgcn_mfma_f32_16x16x32_bf16(ah[kt], bh, acc, 0, 0, 0);
        }
        #pragma unroll
        for (int reg = 0; reg < 4; reg++) {
            float v = acc[reg] * dv[reg];
            int pk = __builtin_amdgcn_cvt_pk_fp8_f32(v, v, 0, false);
            ldsrow[(quad * 4 + reg) * 128 + nt * 16 + m16] = (unsigned char)(pk & 0xFF);
        }
    }
    __syncthreads();
    const uint32_t* l32 = (const uint32_t*)ldsrow;
    #pragma unroll
    for (int i = 0; i < 8; i++) {
        int idx = i * 64 + l;
        int row = idx >> 5;
        int grow = r0 + row;
        if (grow < n) hs8[grow * 32 + (idx & 31)] = l32[idx];
    }
}

// ---- fused: scatter [0,SCB) || GEMM layer-1 [SCB,..) --------------------
__launch_bounds__(256)
__global__ void k_sg(const uint32_t* __restrict__ ebuf, const int* __restrict__ bcnt,
                     int* __restrict__ cursor, unsigned short* __restrict__ col,
                     int E,
                     const void* __restrict__ X,
                     const unsigned short* __restrict__ Wth,
                     const float* __restrict__ dinv,
                     uint32_t* __restrict__ hs8, int n) {
    __shared__ unsigned char lds8[4][16 * 128];
    int b = blockIdx.x;
    if (b < SCB) {
        int p = b & 7;
        int nb = SCB >> 3;
        int cnt = bcnt[p]; if (cnt > CAP) cnt = CAP;
        const uint32_t* eb = ebuf + (size_t)p * CAP;
        for (int i = (b >> 3) * 256 + threadIdx.x; i < cnt; i += nb * 256) {
            uint32_t e = eb[i];
            int pos = atomicAdd(&cursor[e >> 16], 1);
            if ((unsigned)pos < (unsigned)E) col[pos] = (unsigned short)(e & 0xFFFF);
        }
        return;
    }
    int wave = threadIdx.x >> 6;
    int l = threadIdx.x & 63;
    gemm_body(X, Wth, dinv, hs8, n, (b - SCB) * 4 + wave, l, lds8[wave]);
}

// ---- fused agg-1 + GEMM-2: block owns 16 nodes --------------------------
__launch_bounds__(256)
__global__ void k_agg1gemm2(const unsigned short* __restrict__ hsv,
                            const int* __restrict__ row_ptr,
                            const unsigned short* __restrict__ col,
                            const float* __restrict__ dinv,
                            const float* __restrict__ bias,
                            const unsigned short* __restrict__ Wth2,
                            uint32_t* __restrict__ hs8out, int n, int E) {
    __shared__ unsigned short actlds[16 * 136];   // stride 136: bank-safe
    __shared__ unsigned char pack[16 * 128];
    int wave = threadIdx.x >> 6;
    int lane = threadIdx.x & 63;
    int tile0 = blockIdx.x * 16;

    for (int i = 0; i < 4; i++) {
        int node = tile0 + wave * 4 + i;
        bool active = (node < n);
        int nd = active ? node : 0;

        f32x2 sf = __builtin_amdgcn_cvt_pk_f32_fp8((int)hsv[nd * 64 + lane], false);
        float a0 = sf.x, a1 = sf.y;

        int e = row_ptr[nd];
        int end = active ? row_ptr[nd + 1] : e;
        if (e < 0) e = 0;
        if (end > E) end = E;

        for (; e + 8 <= end; e += 8) {
            unsigned si[8];
            #pragma unroll
            for (int j = 0; j < 8; j++) si[j] = (unsigned)col[e + j];
            int uu[8];
            #pragma unroll
            for (int j = 0; j < 8; j++) uu[j] = hsv[si[j] * 64 + lane];
            #pragma unroll
            for (int j = 0; j < 8; j++) {
                f32x2 f = __builtin_amdgcn_cvt_pk_f32_fp8(uu[j], false);
                a0 += f.x;
                a1 += f.y;
            }
        }
        for (; e < end; ++e) {
            unsigned s0 = (unsigned)col[e];
            f32x2 f = __builtin_amdgcn_cvt_pk_f32_fp8((int)hsv[s0 * 64 + lane], false);
            a0 += f.x;
            a1 += f.y;
        }

        float dv = dinv[nd];
        float2 bu = ((const float2*)bias)[lane];
        float r0 = fmaxf(dv * a0 + bu.x, 0.f);
        float r1 = fmaxf(dv * a1 + bu.y, 0.f);
        if (!active) { r0 = 0.f; r1 = 0.f; }
        int row = wave * 4 + i;
        actlds[row * 136 + 2 * lane]     = f2bf(r0);
        actlds[row * 136 + 2 * lane + 1] = f2bf(r1);
    }
    __syncthreads();

    // Phase B: MFMA tile (A from actlds; 16B-aligned: 136*2=272=16*17)
    int quad = lane >> 4;
    int m16 = lane & 15;
    bf16x8 ah[4];
    #pragma unroll
    for (int kt = 0; kt < 4; kt++) {
        const unsigned short* p = &actlds[m16 * 136 + kt * 32 + quad * 8];
        ah[kt] = __builtin_bit_cast(bf16x8, *(const int4*)p);
    }
    float dv4[4];
    #pragma unroll
    for (int reg = 0; reg < 4; reg++) {
        int row = tile0 + quad * 4 + reg;
        if (row > n - 1) row = n - 1;
        dv4[reg] = dinv[row];
    }
    const int4* Wvh = (const int4*)Wth2;
    #pragma unroll
    for (int ntl = 0; ntl < 2; ntl++) {
        int nt = wave * 2 + ntl;
        f32x4 acc = {0.f, 0.f, 0.f, 0.f};
        int brow = (nt * 16 + m16) * 16;
        #pragma unroll
        for (int kt = 0; kt < 4; kt++) {
            bf16x8 bh = __builtin_bit_cast(bf16x8, Wvh[brow + kt * 4 + quad]);
            acc = __builtin_amdgcn_mfma_f32_16x16x32_bf16(ah[kt], bh, acc, 0, 0, 0);
        }
        #pragma unroll
        for (int reg = 0; reg < 4; reg++) {
            float v = acc[reg] * dv4[reg];
            int pk = __builtin_amdgcn_cvt_pk_fp8_f32(v, v, 0, false);
            pack[(quad * 4 + reg) * 128 + nt * 16 + m16] = (unsigned char)(pk & 0xFF);
        }
    }
    __syncthreads();
    const uint32_t* l32 = (const uint32_t*)pack;
    #pragma unroll
    for (int i = 0; i < 2; i++) {
        int idx = i * 256 + threadIdx.x;   // 0..511
        int row = idx >> 5;
        int grow = tile0 + row;
        if (grow < n) hs8out[grow * 32 + (idx & 31)] = l32[idx];
    }
}

// ---- Pull aggregation layer-2 (fp8 hs, pre-scaled) -> pooled partials ---
__launch_bounds__(256)
__global__ void k_agg(const unsigned short* __restrict__ hsv,
                      const int* __restrict__ row_ptr,
                      const unsigned short* __restrict__ col,
                      const float* __restrict__ dinv,
                      const float* __restrict__ bias,
                      float* __restrict__ partial, int n, int E) {
    __shared__ float pl[4][128];
    int wave = threadIdx.x >> 6;
    int lane = threadIdx.x & 63;
    int node = blockIdx.x * 4 + wave;
    bool active = (node < n);
    int nd = active ? node : 0;

    f32x2 sf = __builtin_amdgcn_cvt_pk_f32_fp8((int)hsv[nd * 64 + lane], false);
    float a0 = sf.x, a1 = sf.y;

    int e = row_ptr[nd];
    int end = active ? row_ptr[nd + 1] : e;
    if (e < 0) e = 0;
    if (end > E) end = E;

    for (; e + 8 <= end; e += 8) {
        unsigned si[8];
        #pragma unroll
        for (int j = 0; j < 8; j++) si[j] = (unsigned)col[e + j];
        int uu[8];
        #pragma unroll
        for (int j = 0; j < 8; j++) uu[j] = hsv[si[j] * 64 + lane];
        #pragma unroll
        for (int j = 0; j < 8; j++) {
            f32x2 f = __builtin_amdgcn_cvt_pk_f32_fp8(uu[j], false);
            a0 += f.x;
            a1 += f.y;
        }
    }
    for (; e < end; ++e) {
        unsigned s0 = (unsigned)col[e];
        f32x2 f = __builtin_amdgcn_cvt_pk_f32_fp8((int)hsv[s0 * 64 + lane], false);
        a0 += f.x;
        a1 += f.y;
    }

    float dv = dinv[nd];
    float2 bu = ((const float2*)bias)[lane];
    float r0 = fmaxf(dv * a0 + bu.x, 0.f);
    float r1 = fmaxf(dv * a1 + bu.y, 0.f);
    if (!active) { r0 = 0.f; r1 = 0.f; }

    pl[wave][2 * lane]     = r0;
    pl[wave][2 * lane + 1] = r1;
    __syncthreads();
    int t = threadIdx.x;
    if (t < 128) {
        float ps = pl[0][t] + pl[1][t] + pl[2][t] + pl[3][t];
        partial[blockIdx.x * 128 + t] = ps;
    }
}

// ---- fused pooled reduce + FC (last-block pattern) ----------------------
__launch_bounds__(256)
__global__ void k_redfinal(const float* __restrict__ partial, float* __restrict__ pooled,
                           int* __restrict__ done,
                           const float* __restrict__ Wfcf, const float* __restrict__ bfcf,
                           const void* __restrict__ x, void* __restrict__ out,
                           int n, int nbrows, int gblocks) {
    __shared__ float red[8][128];
    int t = threadIdx.x;
    int chunk = (nbrows + gblocks - 1) / gblocks;
    int r0 = blockIdx.x * chunk;
    int r1 = r0 + chunk;
    if (r1 > nbrows) r1 = nbrows;

    float4 acc = {0.f, 0.f, 0.f, 0.f};
    const float4* p4 = (const float4*)partial;
    for (int i = r0 * 32 + t; i < r1 * 32; i += 256) {
        float4 v = p4[i];
        acc.x += v.x; acc.y += v.y; acc.z += v.z; acc.w += v.w;
    }
    int g = t >> 5;
    int fb = (t & 31) * 4;
    red[g][fb]     = acc.x;
    red[g][fb + 1] = acc.y;
    red[g][fb + 2] = acc.z;
    red[g][fb + 3] = acc.w;
    __syncthreads();
    if (t < 128) {
        float s = red[0][t] + red[1][t] + red[2][t] + red[3][t]
                + red[4][t] + red[5][t] + red[6][t] + red[7][t];
        atomicAdd(&pooled[t], s);
    }
    __threadfence();
    __shared__ int lastf;
    if (t == 0) lastf = (atomicAdd(done, 1) == gblocks - 1) ? 1 : 0;
    __syncthreads();
    if (!lastf) return;

    __shared__ int hits;
    __shared__ float pv[128];
    if (t == 0) hits = 0;
    __syncthreads();
    unsigned ew = (((const uint32_t*)x)[t] >> 7) & 0xFFu;
    unsigned long long bl = __ballot(ew >= 0x60u && ew <= 0x90u);
    if ((t & 63) == 0) atomicAdd(&hits, (int)__popcll(bl));
    if (t < 128)
        pv[t] = __hip_atomic_load(&pooled[t], __ATOMIC_RELAXED,
                                  __HIP_MEMORY_SCOPE_AGENT);
    __syncthreads();
    int isbf = (2 * hits > 256);
    if (t < 32) {
        float s = 0.f;
        for (int c = 0; c < 128; ++c) s += pv[c] * Wfcf[c * 32 + t];
        s = s * (1.0f / (float)n) + bfcf[t];
        if (isbf) ((unsigned short*)out)[t] = f2bf(s);
        else      ((float*)out)[t] = s;
    }
}

// ---- Launch -------------------------------------------------------------

extern "C" void kernel_launch(void* const* d_in, const int* in_sizes, int n_in,
                              void* d_out, int out_size, void* d_ws, size_t ws_size,
                              hipStream_t stream) {
    const void* x   = d_in[0];
    const int*  ei  = (const int*)d_in[1];
    const void* W1  = d_in[2];
    const void* b1  = d_in[3];
    const void* W2  = d_in[4];
    const void* b2  = d_in[5];
    const void* Wfc = d_in[6];
    const void* bfc = d_in[7];

    const int n = in_sizes[0] / FEAT;    // 50000 (< 65536: 16-bit id packing)
    const int E = in_sizes[1] / 2;       // 800000
    const int nagg = (n + 3) / 4;        // 12500
    const int ntile = (n + 15) / 16;     // 3125
    const int psz  = (n + 7) / 8;        // 6250
    const int nscan = (n + 255) / 256;   // 196
    const int NE   = (E + ECH - 1) / ECH;// 391
    const int gemm_grid = (ntile + 3) / 4; // 782

    char* ws = (char*)d_ws;
    uint32_t*       hs8     = (uint32_t*)(ws);                     // 6.4MB used
    uint32_t*       hs8b    = (uint32_t*)(ws + 12800000);          // 6.4MB (layer-2 hs)
    float*          partial = (float*)(ws + 25600000);             // 6.4MB used
    unsigned short* col     = (unsigned short*)(ws + 38400000);    // 1.6MB (ushort ids)
    uint32_t*       ebuf    = (uint32_t*)(ws + 41600000);          // 6.4MB (8*CAP packed)
    int*            deg     = (int*)(ws + 54400000);               // 200,000
    int*            row_ptr = (int*)(ws + 54600000);               // 200,016
    int*            cursor  = (int*)(ws + 54800016);               // 200,000
    float*          dinv    = (float*)(ws + 55000016);             // 200,000
    unsigned short* Wth1    = (unsigned short*)(ws + 55200016);    // 32,768
    unsigned short* Wth2    = (unsigned short*)(ws + 55232784);    // 32,768
    float*          b1f     = (float*)(ws + 55265552);             // 512
    float*          b2f     = (float*)(ws + 55266064);             // 512
    float*          Wfcf    = (float*)(ws + 55266576);             // 16,384
    float*          bfcf    = (float*)(ws + 55282960);             // 128
    // zero region (one memset): pooled | bcnt | done(+pad) | bsum
    float*          pooled  = (float*)(ws + 55283088);             // 512
    int*            bcnt    = (int*)(ws + 55283600);               // 32
    int*            done    = (int*)(ws + 55283632);               // 4 (+12 pad)
    int*            bsum    = (int*)(ws + 55283648);               // 784

    if (ws_size < 55284448) return;  // diagnostic: zero output => ws too small

    hipMemsetAsync(pooled, 0, 1344, stream);

    // 1) fused prep: edge decode+bucket (+deg zero) | weight/bias prep
    k_prep<<<NE + 82, 256, 0, stream>>>(ei, ebuf, bcnt, deg, E, n, psz, NE,
                                        W1, W2, b1, b2, Wfc, bfc,
                                        Wth1, Wth2, b1f, b2f, Wfcf, bfcf);
    // 2) CSR: degree -> scan (boundaries are the cheap sync -- R11)
    k_degp<<<512, 256, 0, stream>>>(ebuf, bcnt, deg);
    k_bsum<<<nscan, 256, 0, stream>>>(deg, bsum, dinv, n);
    k_bapply2<<<nscan, 256, 0, stream>>>(deg, bsum, row_ptr, cursor, n, nscan);
    // 3) fused: scatter || GEMM layer-1 (both dep only on bapply)
    k_sg<<<SCB + gemm_grid, 256, 0, stream>>>(ebuf, bcnt, cursor, col, E,
                                              x, Wth1, dinv, hs8, n);
    // 4) fused agg-1 + GEMM-2 (act stays in LDS)
    k_agg1gemm2<<<ntile, 256, 0, stream>>>((const unsigned short*)hs8, row_ptr,
                                           col, dinv, b1f, Wth2, hs8b, n, E);
    // 5) agg-2 -> pooled partials
    k_agg<<<nagg, 256, 0, stream>>>((const unsigned short*)hs8b, row_ptr, col,
                                    dinv, b2f, partial, n, E);
    // 6) fused pooled-reduce + FC
    k_redfinal<<<100, 256, 0, stream>>>(partial, pooled, done, Wfcf, bfcf,
                                        x, d_out, n, nagg, 100);
}